// Round 12
// baseline (112.094 us; speedup 1.0000x reference)
//
#include <hip/hip_runtime.h>
#include <hip/hip_bf16.h>

// Problem dims (fixed)
#define MROWS 8192      // B*T
#define HIDD  512
#define KD    256
#define VDIM  512
#define NH    4
#define HK    64
#define HV    128
#define TSEQ  2048
#define BATCH 4
#define NC    32        // number of chunks
#define CHK   64        // chunk length
#define LDP   1536      // proj row stride: q[0,256) k[256,512) v[512,1024) g[1024,1536)

typedef __attribute__((ext_vector_type(8))) short bf16x8;
typedef __attribute__((ext_vector_type(4))) float f32x4;
typedef __attribute__((address_space(1))) const void gas_t;
typedef __attribute__((address_space(3))) void las_t;

#define MFMA(a, b, c) __builtin_amdgcn_mfma_f32_16x16x32_bf16(a, b, c, 0, 0, 0)

__device__ __forceinline__ void f2hl(float x, __hip_bfloat16& h, __hip_bfloat16& l) {
  h = __float2bfloat16(x);
  l = __float2bfloat16(x - __bfloat162float(h));
}

// ---------------------------------------------------------------------------
// prep: blocks [0,512)   — fused cast_x + g1 = X @ Wgk1^T
//       blocks [512,1536) — cast W{q,k,v,g,o} into Wcat (bf16)
// ---------------------------------------------------------------------------
__global__ __launch_bounds__(256) void prep(
    const float* __restrict__ X,
    const float* __restrict__ Wq, const float* __restrict__ Wk,
    const float* __restrict__ Wv, const float* __restrict__ Wg,
    const float* __restrict__ Wo, const float* __restrict__ Wgk1,
    __hip_bfloat16* __restrict__ Xb, __hip_bfloat16* __restrict__ Wcat,
    float* __restrict__ g1) {
  __shared__ float w1f[8192];   // Wgk1 [16][512] flat
  const int bid = blockIdx.x;
  const int tid = threadIdx.x;
  if (bid < 512) {
#pragma unroll
    for (int e = 0; e < 8; ++e) {
      const int i = (e * 256 + tid) * 4;
      *(float4*)&w1f[i] = *(const float4*)(Wgk1 + i);
    }
    __syncthreads();
    const int r = tid >> 4, j = tid & 15;
    const int row = bid * 16 + r;
    const float* xp = X + (size_t)row * HIDD;
    __hip_bfloat16* xbp = Xb + (size_t)row * HIDD;
    float acc[16];
#pragma unroll
    for (int c = 0; c < 16; ++c) acc[c] = 0.f;
#pragma unroll
    for (int i = 0; i < 8; ++i) {
      const int k0 = i * 64 + j * 4;
      const float4 xv = *(const float4*)(xp + k0);
      __hip_bfloat16 o[4] = {__float2bfloat16(xv.x), __float2bfloat16(xv.y),
                             __float2bfloat16(xv.z), __float2bfloat16(xv.w)};
      *(short4*)(xbp + k0) = *(const short4*)o;
#pragma unroll
      for (int c = 0; c < 16; ++c) {
        const float4 wv = *(const float4*)&w1f[c * 512 + k0];
        acc[c] += xv.x * wv.x + xv.y * wv.y + xv.z * wv.z + xv.w * wv.w;
      }
    }
#pragma unroll
    for (int c = 0; c < 16; ++c) {
      acc[c] += __shfl_xor(acc[c], 1);
      acc[c] += __shfl_xor(acc[c], 2);
      acc[c] += __shfl_xor(acc[c], 4);
      acc[c] += __shfl_xor(acc[c], 8);
    }
    if (j == 0) {
      float* gp = g1 + (size_t)row * 16;
#pragma unroll
      for (int e = 0; e < 4; ++e)
        *(float4*)(gp + e * 4) = make_float4(acc[e * 4], acc[e * 4 + 1],
                                             acc[e * 4 + 2], acc[e * 4 + 3]);
    }
  } else {
    const int i = ((bid - 512) * 256 + tid) * 4;
    const float* src; int off;
    if (i < 131072)      { src = Wq; off = 0; }
    else if (i < 262144) { src = Wk; off = 131072; }
    else if (i < 524288) { src = Wv; off = 262144; }
    else if (i < 786432) { src = Wg; off = 524288; }
    else                 { src = Wo; off = 786432; }
    const float4 v = *(const float4*)(src + (i - off));
    __hip_bfloat16 o[4] = {__float2bfloat16(v.x), __float2bfloat16(v.y),
                           __float2bfloat16(v.z), __float2bfloat16(v.w)};
    *(short4*)(Wcat + i) = *(const short4*)o;
  }
}

// ---------------------------------------------------------------------------
// gemm_gate: blocks [0,192)   — bf16 MFMA GEMM, 256x256 tile, 8 waves,
//   BK=64 split into two K-halves (kh=32). Double-buffered LDS (128 KiB).
//   4 phases per K-tile; each phase stages ONE half-tile (2 gload_lds/thr),
//   counted vmcnt(4) + raw s_barrier at ph0/ph2 only -> 2 half-tiles stay in
//   flight across barriers. Swizzle: LDS slot ^ (r&3) ^ ((r>>2)&3) on 64B
//   rows, inverse-applied on global source. setprio around MFMA clusters.
//            blocks [192,256) — gate_cumsum, 2 chunks per 512-thr block.
// ---------------------------------------------------------------------------
__global__ __launch_bounds__(512, 2) void gemm_gate(
    const __hip_bfloat16* __restrict__ A, const __hip_bfloat16* __restrict__ Bw,
    float* __restrict__ C,
    const float* __restrict__ g1, const float* __restrict__ W2,
    const float* __restrict__ bias, float* __restrict__ Bcum,
    float* __restrict__ dvec) {
  __shared__ __align__(16) char smem[131072];   // A: [2buf][2kh][256][64B], B: +65536
  const int tid = threadIdx.x;
  const int bid = blockIdx.x;
  if (bid < 192) {
    const int wid = tid >> 6, lane = tid & 63;
    const int swz = (bid & 7) * 24 + (bid >> 3);          // bijective (192%8==0)
    const int m0 = (swz / 6) * 256;
    const int n0 = (swz % 6) * 256;
    const int wm = (wid >> 2) * 128;        // wave M offset (2 M-waves)
    const int wn = (wid & 3) * 64;          // wave N offset (4 N-waves)
    const int lr = lane & 15, s4 = lane >> 4;
    const int K = HIDD;
    f32x4 acc[8][4];
#pragma unroll
    for (int f = 0; f < 8; ++f)
#pragma unroll
      for (int n = 0; n < 4; ++n) acc[f][n] = (f32x4){0.f, 0.f, 0.f, 0.f};

    const int srow  = lane >> 2;            // 0..15 row within wave's group
    const int sslot = lane & 3;             // 16B slot within 64B row

    auto stage_half = [&](const __hip_bfloat16* gbase, int row0, int lds_off,
                          int buf, int kh, int kt) {
#pragma unroll
      for (int i = 0; i < 2; ++i) {
        const int r = i * 128 + wid * 16 + srow;
        const int sg = sslot ^ (r & 3) ^ ((r >> 2) & 3);  // inverse swizzle on src
        __builtin_amdgcn_global_load_lds(
            (gas_t*)(gbase + (size_t)(row0 + r) * K + kt * 64 + kh * 32 + sg * 8),
            (las_t*)(smem + lds_off + buf * 32768 + kh * 16384 +
                     (i * 128 + wid * 16) * 64),
            16, 0, 0);
      }
    };
    auto rdA = [&](int f, int p, int kh) -> bf16x8 {
      const int r = wm + f * 16 + lr;
      const int sl = s4 ^ (r & 3) ^ ((r >> 2) & 3);
      return *(const bf16x8*)(smem + p * 32768 + kh * 16384 + r * 64 + sl * 16);
    };
    auto rdB = [&](int n, int p, int kh) -> bf16x8 {
      const int r = wn + n * 16 + lr;
      const int sl = s4 ^ (r & 3) ^ ((r >> 2) & 3);
      return *(const bf16x8*)(smem + 65536 + p * 32768 + kh * 16384 + r * 64 + sl * 16);
    };

    // prologue: K-tile 0, all 4 half-tiles into buf0 (8 loads/thread)
    stage_half(A,  m0, 0,     0, 0, 0);
    stage_half(Bw, n0, 65536, 0, 0, 0);
    stage_half(A,  m0, 0,     0, 1, 0);
    stage_half(Bw, n0, 65536, 0, 1, 0);

    for (int t = 0; t < 8; ++t) {
      const int p = t & 1;
      const bool more = (t < 7);
      bf16x8 af[4], bfr[4];
      // ---- ph0: need A/B[t] kh0 (issued 4 phases ago; 4 newer loads in flight)
      asm volatile("s_waitcnt vmcnt(4)" ::: "memory");
      __builtin_amdgcn_s_barrier();
      __builtin_amdgcn_sched_barrier(0);
      if (more) stage_half(A, m0, 0, p ^ 1, 0, t + 1);
#pragma unroll
      for (int f = 0; f < 4; ++f) af[f] = rdA(f, p, 0);
#pragma unroll
      for (int n = 0; n < 4; ++n) bfr[n] = rdB(n, p, 0);
      asm volatile("s_waitcnt lgkmcnt(0)" ::: "memory");
      __builtin_amdgcn_sched_barrier(0);
      __builtin_amdgcn_s_setprio(1);
#pragma unroll
      for (int f = 0; f < 4; ++f)
#pragma unroll
        for (int n = 0; n < 4; ++n) acc[f][n] = MFMA(af[f], bfr[n], acc[f][n]);
      __builtin_amdgcn_s_setprio(0);
      // ---- ph1 (B kh0 frags reused from registers)
      if (more) stage_half(Bw, n0, 65536, p ^ 1, 0, t + 1);
#pragma unroll
      for (int f = 0; f < 4; ++f) af[f] = rdA(4 + f, p, 0);
      asm volatile("s_waitcnt lgkmcnt(0)" ::: "memory");
      __builtin_amdgcn_sched_barrier(0);
      __builtin_amdgcn_s_setprio(1);
#pragma unroll
      for (int f = 0; f < 4; ++f)
#pragma unroll
        for (int n = 0; n < 4; ++n) acc[4 + f][n] = MFMA(af[f], bfr[n], acc[4 + f][n]);
      __builtin_amdgcn_s_setprio(0);
      // ---- ph2: need A/B[t] kh1
      if (more) { asm volatile("s_waitcnt vmcnt(4)" ::: "memory"); }
      else      { asm volatile("s_waitcnt vmcnt(0)" ::: "memory"); }
      __builtin_amdgcn_s_barrier();
      __builtin_amdgcn_sched_barrier(0);
      if (more) stage_half(A, m0, 0, p ^ 1, 1, t + 1);
#pragma unroll
      for (int f = 0; f < 4; ++f) af[f] = rdA(f, p, 1);
#pragma unroll
      for (int n = 0; n < 4; ++n) bfr[n] = rdB(n, p, 1);
      asm volatile("s_waitcnt lgkmcnt(0)" ::: "memory");
      __builtin_amdgcn_sched_barrier(0);
      __builtin_amdgcn_s_setprio(1);
#pragma unroll
      for (int f = 0; f < 4; ++f)
#pragma unroll
        for (int n = 0; n < 4; ++n) acc[f][n] = MFMA(af[f], bfr[n], acc[f][n]);
      __builtin_amdgcn_s_setprio(0);
      // ---- ph3
      if (more) stage_half(Bw, n0, 65536, p ^ 1, 1, t + 1);
#pragma unroll
      for (int f = 0; f < 4; ++f) af[f] = rdA(4 + f, p, 1);
      asm volatile("s_waitcnt lgkmcnt(0)" ::: "memory");
      __builtin_amdgcn_sched_barrier(0);
      __builtin_amdgcn_s_setprio(1);
#pragma unroll
      for (int f = 0; f < 4; ++f)
#pragma unroll
        for (int n = 0; n < 4; ++n) acc[4 + f][n] = MFMA(af[f], bfr[n], acc[4 + f][n]);
      __builtin_amdgcn_s_setprio(0);
    }
    // epilogue: C/D layout col=lane&15, row=(lane>>4)*4+i
    const int col = lane & 15;
    const int rb  = s4 * 4;
#pragma unroll
    for (int f = 0; f < 8; ++f)
#pragma unroll
      for (int n = 0; n < 4; ++n) {
        float* cp = C + (size_t)(m0 + wm + f * 16 + rb) * LDP + n0 + wn + n * 16 + col;
        cp[0 * (size_t)LDP] = acc[f][n][0];
        cp[1 * (size_t)LDP] = acc[f][n][1];
        cp[2 * (size_t)LDP] = acc[f][n][2];
        cp[3 * (size_t)LDP] = acc[f][n][3];
      }
  } else {
    // ---- gate_cumsum: 64 blocks x 512 thr, 2 chunks per block ----
    const int gb = bid - 192;
    const int sub = tid >> 8;          // 0/1 -> chunk within pair
    const int stid = tid & 255;
    const int cc = gb * 2 + sub;       // 0..127
    const int c = cc & 31, b = cc >> 5;
    float (*g1s)[16] = (float(*)[16])(smem + sub * 4096);
    const size_t rowbase = (size_t)b * TSEQ + (size_t)c * CHK;
    {
      const int idx = stid * 4;                 // 1024 floats per sub
      const int t = idx >> 4, j = idx & 15;
      *(float4*)&g1s[t][j] = *(const float4*)&g1[(rowbase + t) * 16 + j];
    }
    float w[16];
#pragma unroll
    for (int e4 = 0; e4 < 4; ++e4)
      *(float4*)&w[e4 * 4] = *(const float4*)&W2[(size_t)stid * 16 + e4 * 4];
    const float s0 = bias[stid];
    __syncthreads();
    float cum = 0.f;
    for (int t = 0; t < CHK; ++t) {
      float s = s0;
#pragma unroll
      for (int j = 0; j < 16; ++j) s += g1s[t][j] * w[j];
      const float a = fabsf(s);
      const float ls = fminf(s, 0.f) - log1pf(expf(-a));
      cum += ls * (1.0f / 16.0f);
      Bcum[(rowbase + t) * KD + stid] = cum;
    }
    const int h = stid >> 6, kk = stid & 63;
    dvec[((size_t)(b * NH + h) * NC + c) * HK + kk] = expf(cum);
  }
}

// ---------------------------------------------------------------------------
// gemm_n64: C[M,N] = A @ W^T, 128x64 tiles (512 blocks), BK=64,
// single-buffered 2-barrier structure, row-XOR swizzle (128B rows).
// ---------------------------------------------------------------------------
__global__ __launch_bounds__(256) void gemm_n64(
    const __hip_bfloat16* __restrict__ A, const __hip_bfloat16* __restrict__ Bw,
    float* __restrict__ C, int K, int ldc) {
  __shared__ __hip_bfloat16 As[128 * 64];  // 16 KB
  __shared__ __hip_bfloat16 Bs[64 * 64];   //  8 KB
  const int tid = threadIdx.x;
  const int wid = tid >> 6, lane = tid & 63;
  const int q8 = gridDim.x >> 3;
  const int swz = (blockIdx.x & 7) * q8 + (blockIdx.x >> 3);
  const int m0 = (swz >> 3) * 128, n0 = (swz & 7) * 64;
  const int wm = (wid >> 1) * 64, wn = (wid & 1) * 32;
  f32x4 acc[4][2];
#pragma unroll
  for (int m = 0; m < 4; ++m)
#pragma unroll
    for (int n = 0; n < 2; ++n) acc[m][n] = (f32x4){0.f, 0.f, 0.f, 0.f};

  const int srow_off = lane >> 3;
  const int scb      = (lane & 7) * 16;

  const int NT = K >> 6;
  for (int t = 0; t < NT; ++t) {
    const int k0 = t * 64;
#pragma unroll
    for (int i = 0; i < 4; ++i) {
      const int rbase = wid * 32 + i * 8;
      const int row = rbase + srow_off;
      const int src_cb = scb ^ ((row & 7) << 4);
      __builtin_amdgcn_global_load_lds(
          (gas_t*)(A + (size_t)(m0 + row) * K + k0 + (src_cb >> 1)),
          (las_t*)(As + rbase * 64), 16, 0, 0);
    }
#pragma unroll
    for (int i = 0; i < 2; ++i) {
      const int rbase = wid * 16 + i * 8;
      const int row = rbase + srow_off;
      const int src_cb = scb ^ ((row & 7) << 4);
      __builtin_amdgcn_global_load_lds(
          (gas_t*)(Bw + (size_t)(n0 + row) * K + k0 + (src_cb >> 1)),
          (las_t*)(Bs + rbase * 64), 16, 0, 0);
    }
    __syncthreads();
#pragma unroll
    for (int s = 0; s < 2; ++s) {
      const int kg = (s << 6) | ((lane >> 4) << 4);
      bf16x8 af[4], bfr[2];
#pragma unroll
      for (int m = 0; m < 4; ++m) {
        const int row = wm + m * 16 + (lane & 15);
        const int cb  = kg ^ ((row & 7) << 4);
        af[m] = *(const bf16x8*)((const char*)As + row * 128 + cb);
      }
#pragma unroll
      for (int n = 0; n < 2; ++n) {
        const int row = wn + n * 16 + (lane & 15);
        const int cb  = kg ^ ((row & 7) << 4);
        bfr[n] = *(const bf16x8*)((const char*)Bs + row * 128 + cb);
      }
#pragma unroll
      for (int m = 0; m < 4; ++m)
#pragma unroll
        for (int n = 0; n < 2; ++n)
          acc[m][n] = MFMA(af[m], bfr[n], acc[m][n]);
    }
    __syncthreads();
  }
  const int col = lane & 15;
  const int rb  = (lane >> 4) * 4;
#pragma unroll
  for (int m = 0; m < 4; ++m)
#pragma unroll
    for (int n = 0; n < 2; ++n) {
      float* cp = C + (size_t)(m0 + wm + m * 16 + rb) * ldc + n0 + wn + n * 16 + col;
      cp[0 * (size_t)ldc] = acc[m][n][0];
      cp[1 * (size_t)ldc] = acc[m][n][1];
      cp[2 * (size_t)ldc] = acc[m][n][2];
      cp[3 * (size_t)ldc] = acc[m][n][3];
    }
}

// ---------------------------------------------------------------------------
// Per-chunk summary via MFMA hi/lo:
//   dST[v][kk] = sum_t V[t][v] * k[t][kk]*exp(B63[kk]-B_t[kk])
// Grid (32,4,4), 256 thr. B from precomputed Bcum.
// ---------------------------------------------------------------------------
__global__ __launch_bounds__(256) void chunk_summary(
    const float* __restrict__ proj, const float* __restrict__ Bcum,
    float* __restrict__ dST) {
  __shared__ float bls[64];
  __shared__ __hip_bfloat16 kTh[64][72], kTl[64][72];   // ktw^T [kk][t]
  __shared__ __hip_bfloat16 vTh[128][72], vTl[128][72]; // V^T  [v][t]
  const int c = blockIdx.x, h = blockIdx.y, b = blockIdx.z;
  const int bh = b * NH + h;
  const int tid = threadIdx.x;
  const size_t rowbase = (size_t)b * TSEQ + (size_t)c * CHK;
  if (tid < 64) bls[tid] = Bcum[(rowbase + 63) * KD + h * HK + tid];
  __syncthreads();
  {
    const int t = tid >> 2;
    const int kk0 = (tid & 3) * 16;
    const float* kp = &proj[(rowbase + t) * LDP + KD + h * HK + kk0];
    const float* Bp = &Bcum[(rowbase + t) * KD + h * HK + kk0];
    float kv[16], Bv[16];
#pragma unroll
    for (int e4 = 0; e4 < 4; ++e4) {
      *(float4*)&kv[e4 * 4] = *(const float4*)(kp + e4 * 4);
      *(float4*)&Bv[e4 * 4] = *(const float4*)(Bp + e4 * 4);
    }
#pragma unroll
    for (int e = 0; e < 16; ++e) {
      const int kk = kk0 + e;
      const float val = kv[e] * expf(bls[kk] - Bv[e]);
      f2hl(val, kTh[kk][t], kTl[kk][t]);
    }
  }
#pragma unroll
  for (int base = 0; base < 8192; base += 1024) {
    const int idx = base + tid * 4;
    const int t = idx >> 7, v = idx & 127;
    const float4 vv = *(const float4*)&proj[(rowbase + t) * LDP + 2 * KD + h * HV + v];
    f2hl(vv.x, vTh[v + 0][t], vTl[v + 0][t]);
    f2hl(vv.y, vTh[v + 1][t], vTl[v + 1][t]);
    f2hl(vv.z, vTh[v + 2][t], vTl[v + 2][t]);
    f2hl(vv.w, vTh[v + 3][t], vTl[v + 3][t]);
  }
  __syncthreads();
  const int wid = tid >> 6, lane = tid & 63;
  const int lr = lane & 15, lkb = (lane >> 4) * 8;
  f32x4 acc[2][4];
#pragma unroll
  for (int m = 0; m < 2; ++m)
#pragma unroll
    for (int n = 0; n < 4; ++n) acc[m][n] = (f32x4){0.f, 0.f, 0.f, 0.f};
#pragma unroll
  for (int ks = 0; ks < 2; ++ks) {
    const int kt = ks * 32 + lkb;
    bf16x8 ah[2], al[2], bh_[4], bl_[4];
#pragma unroll
    for (int m = 0; m < 2; ++m) {
      ah[m] = *(const bf16x8*)&vTh[wid * 32 + m * 16 + lr][kt];
      al[m] = *(const bf16x8*)&vTl[wid * 32 + m * 16 + lr][kt];
    }
#pragma unroll
    for (int n = 0; n < 4; ++n) {
      bh_[n] = *(const bf16x8*)&kTh[n * 16 + lr][kt];
      bl_[n] = *(const bf16x8*)&kTl[n * 16 + lr][kt];
    }
#pragma unroll
    for (int m = 0; m < 2; ++m)
#pragma unroll
      for (int n = 0; n < 4; ++n) {
        acc[m][n] = MFMA(ah[m], bh_[n], acc[m][n]);
        acc[m][n] = MFMA(ah[m], bl_[n], acc[m][n]);
        acc[m][n] = MFMA(al[m], bh_[n], acc[m][n]);
      }
  }
  const int rb = (lane >> 4) * 4;
  float* outb = dST + ((size_t)bh * NC + c) * 8192;
#pragma unroll
  for (int m = 0; m < 2; ++m)
#pragma unroll
    for (int n = 0; n < 4; ++n)
#pragma unroll
      for (int i = 0; i < 4; ++i)
        outb[(wid * 32 + m * 16 + rb + i) * 64 + n * 16 + lr] = acc[m][n][i];
}

// ---------------------------------------------------------------------------
// Inter-chunk state propagation (transposed layout), emits bf16 hi/lo S.
// ---------------------------------------------------------------------------
__global__ __launch_bounds__(256) void state_prop(
    const float* __restrict__ dST, const float* __restrict__ dvec,
    __hip_bfloat16* __restrict__ ShT, __hip_bfloat16* __restrict__ SlT) {
  const int g  = blockIdx.x * 256 + threadIdx.x;  // 0..131071
  const int bh = g >> 13;
  const int el = g & 8191;        // el = v*64 + kk
  const int kk = el & 63;
  float S = 0.f;
  size_t base = (size_t)bh * NC * 8192 + el;
  const float* dv = dvec + (size_t)bh * NC * HK + kk;
  float dnext = dST[base];
  float vnext = dv[0];
  for (int c = 0; c < NC; ++c) {
    const float dcur = dnext, vcur = vnext;
    if (c + 1 < NC) {
      dnext = dST[base + 8192];
      vnext = dv[(size_t)(c + 1) * HK];
    }
    __hip_bfloat16 h, l;
    f2hl(S, h, l);
    ShT[base] = h; SlT[base] = l;
    S = S * vcur + dcur;
    base += 8192;
  }
}

// ---------------------------------------------------------------------------
// Per-chunk output via MFMA hi/lo: o = P@V + (q*scale*e^B)@S_prev, fused
// per-head RMSNorm * gnorm_w * silu(g), emits bf16 og. Grid (32,4,4), 256 thr.
// ---------------------------------------------------------------------------
__global__ __launch_bounds__(256) void chunk_output(
    const float* __restrict__ proj, const float* __restrict__ Bcum,
    const __hip_bfloat16* __restrict__ ShT, const __hip_bfloat16* __restrict__ SlT,
    const float* __restrict__ gnw, __hip_bfloat16* __restrict__ og) {
  __shared__ __align__(16) char smem_co[73984];
  __hip_bfloat16 (*qh)[72]  = (__hip_bfloat16(*)[72])(smem_co);        // [64][72]
  __hip_bfloat16 (*ql)[72]  = (__hip_bfloat16(*)[72])(smem_co + 9216);
  __hip_bfloat16 (*Ph)[72]  = (__hip_bfloat16(*)[72])(smem_co + 18432);
  __hip_bfloat16 (*Pl)[72]  = (__hip_bfloat16(*)[72])(smem_co + 27648);
  __hip_bfloat16 (*kh)[72]  = (__hip_bfloat16(*)[72])(smem_co + 36864); // transient
  __hip_bfloat16 (*kl)[72]  = (__hip_bfloat16(*)[72])(smem_co + 46080);
  __hip_bfloat16 (*vTh)[72] = (__hip_bfloat16(*)[72])(smem_co + 36864); // over kh/kl
  __hip_bfloat16 (*vTl)[72] = (__hip_bfloat16(*)[72])(smem_co + 55296);
  const int c = blockIdx.x, h = blockIdx.y, b = blockIdx.z;
  const int bh = b * NH + h;
  const int tid = threadIdx.x;
  const size_t rowbase = (size_t)b * TSEQ + (size_t)c * CHK;
  // phase 1: qt = q*scale*e^B (hi/lo), kt = k*e^{-B} (hi/lo), B from Bcum
  {
    const int t = tid >> 2;
    const int kk0 = (tid & 3) * 16;
    const float* qp = &proj[(rowbase + t) * LDP + h * HK + kk0];
    const float* Bp = &Bcum[(rowbase + t) * KD + h * HK + kk0];
    float qv[16], kv[16], Bv[16];
#pragma unroll
    for (int e4 = 0; e4 < 4; ++e4) {
      *(float4*)&qv[e4 * 4] = *(const float4*)(qp + e4 * 4);
      *(float4*)&kv[e4 * 4] = *(const float4*)(qp + KD + e4 * 4);
      *(float4*)&Bv[e4 * 4] = *(const float4*)(Bp + e4 * 4);
    }
#pragma unroll
    for (int e = 0; e < 16; ++e) {
      const int kk = kk0 + e;
      f2hl(qv[e] * 0.125f * expf(Bv[e]), qh[t][kk], ql[t][kk]);
      f2hl(kv[e] * expf(-Bv[e]),         kh[t][kk], kl[t][kk]);
    }
  }
  __syncthreads();
  const int wid = tid >> 6, lane = tid & 63;
  const int lr = lane & 15, lkb = (lane >> 4) * 8;
  const int rb = (lane >> 4) * 4;
  // phase 2: P = qt @ kt^T (masked), -> Ph/Pl
  {
    f32x4 pacc[4];
#pragma unroll
    for (int n = 0; n < 4; ++n) pacc[n] = (f32x4){0.f, 0.f, 0.f, 0.f};
#pragma unroll
    for (int ks = 0; ks < 2; ++ks) {
      const int kt = ks * 32 + lkb;
      const bf16x8 aqh = *(const bf16x8*)&qh[wid * 16 + lr][kt];
      const bf16x8 aql = *(const bf16x8*)&ql[wid * 16 + lr][kt];
#pragma unroll
      for (int n = 0; n < 4; ++n) {
        const bf16x8 bkh = *(const bf16x8*)&kh[n * 16 + lr][kt];
        const bf16x8 bkl = *(const bf16x8*)&kl[n * 16 + lr][kt];
        pacc[n] = MFMA(aqh, bkh, pacc[n]);
        pacc[n] = MFMA(aqh, bkl, pacc[n]);
        pacc[n] = MFMA(aql, bkh, pacc[n]);
      }
    }
#pragma unroll
    for (int n = 0; n < 4; ++n)
#pragma unroll
      for (int i = 0; i < 4; ++i) {
        const int r = wid * 16 + rb + i;
        const int j = n * 16 + lr;
        const float v = (j <= r) ? pacc[n][i] : 0.f;
        f2hl(v, Ph[r][j], Pl[r][j]);
      }
  }
  __syncthreads();
  // phase 3: V^T hi/lo (overwrites kh/kl)
#pragma unroll
  for (int base = 0; base < 8192; base += 1024) {
    const int idx = base + tid * 4;
    const int t = idx >> 7, v = idx & 127;
    const float4 vv = *(const float4*)&proj[(rowbase + t) * LDP + 2 * KD + h * HV + v];
    f2hl(vv.x, vTh[v + 0][t], vTl[v + 0][t]);
    f2hl(vv.y, vTh[v + 1][t], vTl[v + 1][t]);
    f2hl(vv.z, vTh[v + 2][t], vTl[v + 2][t]);
    f2hl(vv.w, vTh[v + 3][t], vTl[v + 3][t]);
  }
  __syncthreads();
  // phase 4: o = qt@S^T + P@V
  f32x4 oacc[8];
#pragma unroll
  for (int n = 0; n < 8; ++n) oacc[n] = (f32x4){0.f, 0.f, 0.f, 0.f};
  const __hip_bfloat16* Sh = ShT + ((size_t)bh * NC + c) * 8192;
  const __hip_bfloat16* Sl = SlT + ((size_t)bh * NC + c) * 8192;
#pragma unroll
  for (int ks = 0; ks < 2; ++ks) {
    const int kt = ks * 32 + lkb;
    const bf16x8 aqh = *(const bf16x8*)&qh[wid * 16 + lr][kt];
    const bf16x8 aql = *(const bf16x8*)&ql[wid * 16 + lr][kt];
#pragma unroll
    for (int n = 0; n < 8; ++n) {
      const int v = n * 16 + lr;
      const bf16x8 sh = *(const bf16x8*)(Sh + v * 64 + kt);
      const bf16x8 sl = *(const bf16x8*)(Sl + v * 64 + kt);
      oacc[n] = MFMA(aqh, sh, oacc[n]);
      oacc[n] = MFMA(aqh, sl, oacc[n]);
      oacc[n] = MFMA(aql, sh, oacc[n]);
    }
  }
#pragma unroll
  for (int ks = 0; ks < 2; ++ks) {
    const int kt = ks * 32 + lkb;
    const bf16x8 aph = *(const bf16x8*)&Ph[wid * 16 + lr][kt];
    const bf16x8 apl = *(const bf16x8*)&Pl[wid * 16 + lr][kt];
#pragma unroll
    for (int n = 0; n < 8; ++n) {
      const bf16x8 bvh = *(const bf16x8*)&vTh[n * 16 + lr][kt];
      const bf16x8 bvl = *(const bf16x8*)&vTl[n * 16 + lr][kt];
      oacc[n] = MFMA(aph, bvh, oacc[n]);
      oacc[n] = MFMA(aph, bvl, oacc[n]);
      oacc[n] = MFMA(apl, bvh, oacc[n]);
    }
  }
  // epilogue: per-row RMSNorm over 128 v (reduce across 16-lane group)
  float ss[4] = {0.f, 0.f, 0.f, 0.f};
#pragma unroll
  for (int n = 0; n < 8; ++n)
#pragma unroll
    for (int i = 0; i < 4; ++i) ss[i] += oacc[n][i] * oacc[n][i];
#pragma unroll
  for (int i = 0; i < 4; ++i) {
    ss[i] += __shfl_xor(ss[i], 1);
    ss[i] += __shfl_xor(ss[i], 2);
    ss[i] += __shfl_xor(ss[i], 4);
    ss[i] += __shfl_xor(ss[i], 8);
  }
  float rn[4];
#pragma unroll
  for (int i = 0; i < 4; ++i) rn[i] = rsqrtf(ss[i] * (1.0f / 128.0f) + 1e-5f);
#pragma unroll
  for (int n = 0; n < 8; ++n) {
    const int v = n * 16 + lr;
    const float w = gnw[v];  // gnorm_w is [HV], broadcast across heads
#pragma unroll
    for (int i = 0; i < 4; ++i) {
      const size_t grow = rowbase + wid * 16 + rb + i;
      const float g = proj[grow * LDP + 2 * VDIM + h * HV + v];
      const float sil = g / (1.f + expf(-g));
      og[grow * VDIM + h * HV + v] = __float2bfloat16(oacc[n][i] * rn[i] * w * sil);
    }
  }
}

// ---------------------------------------------------------------------------
extern "C" void kernel_launch(void* const* d_in, const int* in_sizes, int n_in,
                              void* d_out, int out_size, void* d_ws, size_t ws_size,
                              hipStream_t stream) {
  const float* X    = (const float*)d_in[0];
  const float* Wq   = (const float*)d_in[1];
  const float* Wk   = (const float*)d_in[2];
  const float* Wv   = (const float*)d_in[3];
  const float* Wgk1 = (const float*)d_in[4];
  const float* Wgk2 = (const float*)d_in[5];
  const float* bgk2 = (const float*)d_in[6];
  const float* gnw  = (const float*)d_in[7];
  const float* Wg   = (const float*)d_in[8];
  const float* Wo   = (const float*)d_in[9];
  float* out = (float*)d_out;

  char* wsb = (char*)d_ws;
  float* proj = (float*)(wsb);                              // 50331648 B
  float* Bcum = (float*)(wsb + 50331648);                   //  8388608 B
  float* g1   = (float*)(wsb + 58720256);                   //   524288 B
  float* dST  = (float*)(wsb + 59244544);                   // 16777216 B
  float* dvec = (float*)(wsb + 76021760);                   //   131072 B
  __hip_bfloat16* ShT  = (__hip_bfloat16*)(wsb + 76152832); //  8388608 B
  __hip_bfloat16* SlT  = (__hip_bfloat16*)(wsb + 84541440); //  8388608 B
  __hip_bfloat16* Xb   = (__hip_bfloat16*)(wsb + 92930048); //  8388608 B
  __hip_bfloat16* Wcat = (__hip_bfloat16*)(wsb + 101318656);//  2097152 B (incl Wo)
  __hip_bfloat16* Wob  = Wcat + 786432;
  __hip_bfloat16* ogb  = (__hip_bfloat16*)dST;  // alias: dST dead before chunk_output

  prep<<<dim3(1536), dim3(256), 0, stream>>>(X, Wq, Wk, Wv, Wg, Wo, Wgk1, Xb, Wcat, g1);
  gemm_gate<<<dim3(256), dim3(512), 0, stream>>>(Xb, Wcat, proj,
                                                 g1, Wgk2, bgk2, Bcum, dvec);
  chunk_summary<<<dim3(NC, NH, BATCH), dim3(256), 0, stream>>>(proj, Bcum, dST);
  state_prop<<<dim3(512), dim3(256), 0, stream>>>(dST, dvec, ShT, SlT);
  chunk_output<<<dim3(NC, NH, BATCH), dim3(256), 0, stream>>>(proj, Bcum, ShT, SlT, gnw, ogb);
  gemm_n64<<<dim3(512), dim3(256), 0, stream>>>(ogb, Wob, out, VDIM, VDIM);
}

// Round 13
// 103.289 us; speedup vs baseline: 1.0852x; 1.0852x over previous
//
#include <hip/hip_runtime.h>
#include <hip/hip_bf16.h>

// Problem dims (fixed)
#define MROWS 8192      // B*T
#define HIDD  512
#define KD    256
#define VDIM  512
#define NH    4
#define HK    64
#define HV    128
#define TSEQ  2048
#define BATCH 4
#define NC    32        // number of chunks
#define CHK   64        // chunk length
#define LDP   1536      // proj row stride: q[0,256) k[256,512) v[512,1024) g[1024,1536)

typedef __attribute__((ext_vector_type(8))) short bf16x8;
typedef __attribute__((ext_vector_type(4))) float f32x4;
typedef __attribute__((address_space(1))) const void gas_t;
typedef __attribute__((address_space(3))) void las_t;

#define MFMA(a, b, c) __builtin_amdgcn_mfma_f32_16x16x32_bf16(a, b, c, 0, 0, 0)

__device__ __forceinline__ void f2hl(float x, __hip_bfloat16& h, __hip_bfloat16& l) {
  h = __float2bfloat16(x);
  l = __float2bfloat16(x - __bfloat162float(h));
}

// ---------------------------------------------------------------------------
// prep: blocks [0,512)   — fused cast_x + g1 = X @ Wgk1^T
//       blocks [512,1536) — cast W{q,k,v,g,o} into Wcat (bf16)
// ---------------------------------------------------------------------------
__global__ __launch_bounds__(256) void prep(
    const float* __restrict__ X,
    const float* __restrict__ Wq, const float* __restrict__ Wk,
    const float* __restrict__ Wv, const float* __restrict__ Wg,
    const float* __restrict__ Wo, const float* __restrict__ Wgk1,
    __hip_bfloat16* __restrict__ Xb, __hip_bfloat16* __restrict__ Wcat,
    float* __restrict__ g1) {
  __shared__ float w1f[8192];   // Wgk1 [16][512] flat
  const int bid = blockIdx.x;
  const int tid = threadIdx.x;
  if (bid < 512) {
#pragma unroll
    for (int e = 0; e < 8; ++e) {
      const int i = (e * 256 + tid) * 4;
      *(float4*)&w1f[i] = *(const float4*)(Wgk1 + i);
    }
    __syncthreads();
    const int r = tid >> 4, j = tid & 15;
    const int row = bid * 16 + r;
    const float* xp = X + (size_t)row * HIDD;
    __hip_bfloat16* xbp = Xb + (size_t)row * HIDD;
    float acc[16];
#pragma unroll
    for (int c = 0; c < 16; ++c) acc[c] = 0.f;
#pragma unroll
    for (int i = 0; i < 8; ++i) {
      const int k0 = i * 64 + j * 4;
      const float4 xv = *(const float4*)(xp + k0);
      __hip_bfloat16 o[4] = {__float2bfloat16(xv.x), __float2bfloat16(xv.y),
                             __float2bfloat16(xv.z), __float2bfloat16(xv.w)};
      *(short4*)(xbp + k0) = *(const short4*)o;
#pragma unroll
      for (int c = 0; c < 16; ++c) {
        const float4 wv = *(const float4*)&w1f[c * 512 + k0];
        acc[c] += xv.x * wv.x + xv.y * wv.y + xv.z * wv.z + xv.w * wv.w;
      }
    }
#pragma unroll
    for (int c = 0; c < 16; ++c) {
      acc[c] += __shfl_xor(acc[c], 1);
      acc[c] += __shfl_xor(acc[c], 2);
      acc[c] += __shfl_xor(acc[c], 4);
      acc[c] += __shfl_xor(acc[c], 8);
    }
    if (j == 0) {
      float* gp = g1 + (size_t)row * 16;
#pragma unroll
      for (int e = 0; e < 4; ++e)
        *(float4*)(gp + e * 4) = make_float4(acc[e * 4], acc[e * 4 + 1],
                                             acc[e * 4 + 2], acc[e * 4 + 3]);
    }
  } else {
    const int i = ((bid - 512) * 256 + tid) * 4;
    const float* src; int off;
    if (i < 131072)      { src = Wq; off = 0; }
    else if (i < 262144) { src = Wk; off = 131072; }
    else if (i < 524288) { src = Wv; off = 262144; }
    else if (i < 786432) { src = Wg; off = 524288; }
    else                 { src = Wo; off = 786432; }
    const float4 v = *(const float4*)(src + (i - off));
    __hip_bfloat16 o[4] = {__float2bfloat16(v.x), __float2bfloat16(v.y),
                           __float2bfloat16(v.z), __float2bfloat16(v.w)};
    *(short4*)(Wcat + i) = *(const short4*)o;
  }
}

// ---------------------------------------------------------------------------
// gemm_gate: blocks [0,128)   — gate_cumsum (runs first, overlaps GEMM)
//            blocks [128,896) — bf16 MFMA GEMM, 128x128 tile, BK=64,
//            single-buffered LDS (stage; sync; compute; sync — the proven
//            2-barrier structure, 8 K-steps), row-XOR swizzled LDS (128B
//            rows: byte ^= (row&7)<<4), XCD-swizzled tile order.
// ---------------------------------------------------------------------------
__global__ __launch_bounds__(256) void gemm_gate(
    const __hip_bfloat16* __restrict__ A, const __hip_bfloat16* __restrict__ Bw,
    float* __restrict__ C, int K, int ldc, int nN, int nTiles,
    const float* __restrict__ g1, const float* __restrict__ W2,
    const float* __restrict__ bias, float* __restrict__ Bcum,
    float* __restrict__ dvec) {
  __shared__ __align__(16) char smem[32768];
  const int tid = threadIdx.x;
  const int bid = blockIdx.x;
  if (bid >= 128) {
    __hip_bfloat16* As = (__hip_bfloat16*)smem;            // [128][64] 16 KB
    __hip_bfloat16* Bs = (__hip_bfloat16*)(smem + 16384);  // [128][64] 16 KB
    const int gbid = bid - 128;
    const int wid = tid >> 6, lane = tid & 63;
    const int q8 = nTiles >> 3;
    const int swz = (gbid & 7) * q8 + (gbid >> 3);
    const int m0 = (swz / nN) * 128, n0 = (swz % nN) * 128;
    const int wm = (wid >> 1) * 64, wn = (wid & 1) * 64;
    f32x4 acc[4][4];
#pragma unroll
    for (int m = 0; m < 4; ++m)
#pragma unroll
      for (int n = 0; n < 4; ++n) acc[m][n] = (f32x4){0.f, 0.f, 0.f, 0.f};

    const int srow_off = lane >> 3;        // 0..7 row within 8-row DMA group
    const int scb      = (lane & 7) * 16;  // linear byte col within 128B row

    const int NT = K >> 6;                 // 8 K-steps
    for (int t = 0; t < NT; ++t) {
      const int k0 = t * 64;
      // stage: per wave 4 A-insts + 4 B-insts, 8 rows each (wave-uniform base)
#pragma unroll
      for (int i = 0; i < 4; ++i) {
        const int rbase = wid * 32 + i * 8;
        const int row = rbase + srow_off;
        const int src_cb = scb ^ ((row & 7) << 4);   // inverse-swizzled source
        __builtin_amdgcn_global_load_lds(
            (gas_t*)(A + (size_t)(m0 + row) * K + k0 + (src_cb >> 1)),
            (las_t*)(As + rbase * 64), 16, 0, 0);
        __builtin_amdgcn_global_load_lds(
            (gas_t*)(Bw + (size_t)(n0 + row) * K + k0 + (src_cb >> 1)),
            (las_t*)(Bs + rbase * 64), 16, 0, 0);
      }
      __syncthreads();
#pragma unroll
      for (int s = 0; s < 2; ++s) {
        const int kg = (s << 6) | ((lane >> 4) << 4);
        bf16x8 af[4], bfr[4];
#pragma unroll
        for (int m = 0; m < 4; ++m) {
          const int row = wm + m * 16 + (lane & 15);
          const int cb  = kg ^ ((row & 7) << 4);
          af[m] = *(const bf16x8*)((const char*)As + row * 128 + cb);
        }
#pragma unroll
        for (int n = 0; n < 4; ++n) {
          const int row = wn + n * 16 + (lane & 15);
          const int cb  = kg ^ ((row & 7) << 4);
          bfr[n] = *(const bf16x8*)((const char*)Bs + row * 128 + cb);
        }
#pragma unroll
        for (int m = 0; m < 4; ++m)
#pragma unroll
          for (int n = 0; n < 4; ++n)
            acc[m][n] = MFMA(af[m], bfr[n], acc[m][n]);
      }
      __syncthreads();
    }
    const int col = lane & 15;
    const int rb  = (lane >> 4) * 4;
#pragma unroll
    for (int m = 0; m < 4; ++m)
#pragma unroll
      for (int n = 0; n < 4; ++n) {
        float* cp = C + (size_t)(m0 + wm + m * 16 + rb) * ldc + n0 + wn + n * 16 + col;
        cp[0 * (size_t)ldc] = acc[m][n][0];
        cp[1 * (size_t)ldc] = acc[m][n][1];
        cp[2 * (size_t)ldc] = acc[m][n][2];
        cp[3 * (size_t)ldc] = acc[m][n][3];
      }
  } else {
    // ---- gate_cumsum ----
    float (*g1s)[16] = (float(*)[16])smem;
    const int gb = bid;
    const int c = gb & 31, b = gb >> 5;
    const size_t rowbase = (size_t)b * TSEQ + (size_t)c * CHK;
    {
      const int idx = tid * 4;                 // 1024 floats total
      const int t = idx >> 4, j = idx & 15;
      *(float4*)&g1s[t][j] = *(const float4*)&g1[(rowbase + t) * 16 + j];
    }
    float w[16];
#pragma unroll
    for (int e4 = 0; e4 < 4; ++e4)
      *(float4*)&w[e4 * 4] = *(const float4*)&W2[(size_t)tid * 16 + e4 * 4];
    const float s0 = bias[tid];
    __syncthreads();
    float cum = 0.f;
    for (int t = 0; t < CHK; ++t) {
      float s = s0;
#pragma unroll
      for (int j = 0; j < 16; ++j) s += g1s[t][j] * w[j];
      const float a = fabsf(s);
      const float ls = fminf(s, 0.f) - log1pf(expf(-a));
      cum += ls * (1.0f / 16.0f);
      Bcum[(rowbase + t) * KD + tid] = cum;
    }
    const int h = tid >> 6, kk = tid & 63;
    dvec[((size_t)(b * NH + h) * NC + c) * HK + kk] = expf(cum);
  }
}

// ---------------------------------------------------------------------------
// gemm_n64: C[M,N] = A @ W^T, 128x64 tiles (512 blocks), BK=64,
// single-buffered 2-barrier structure, row-XOR swizzle (128B rows).
// ---------------------------------------------------------------------------
__global__ __launch_bounds__(256) void gemm_n64(
    const __hip_bfloat16* __restrict__ A, const __hip_bfloat16* __restrict__ Bw,
    float* __restrict__ C, int K, int ldc) {
  __shared__ __hip_bfloat16 As[128 * 64];  // 16 KB
  __shared__ __hip_bfloat16 Bs[64 * 64];   //  8 KB
  const int tid = threadIdx.x;
  const int wid = tid >> 6, lane = tid & 63;
  const int q8 = gridDim.x >> 3;
  const int swz = (blockIdx.x & 7) * q8 + (blockIdx.x >> 3);
  const int m0 = (swz >> 3) * 128, n0 = (swz & 7) * 64;
  const int wm = (wid >> 1) * 64, wn = (wid & 1) * 32;
  f32x4 acc[4][2];
#pragma unroll
  for (int m = 0; m < 4; ++m)
#pragma unroll
    for (int n = 0; n < 2; ++n) acc[m][n] = (f32x4){0.f, 0.f, 0.f, 0.f};

  const int srow_off = lane >> 3;
  const int scb      = (lane & 7) * 16;

  const int NT = K >> 6;
  for (int t = 0; t < NT; ++t) {
    const int k0 = t * 64;
#pragma unroll
    for (int i = 0; i < 4; ++i) {
      const int rbase = wid * 32 + i * 8;
      const int row = rbase + srow_off;
      const int src_cb = scb ^ ((row & 7) << 4);
      __builtin_amdgcn_global_load_lds(
          (gas_t*)(A + (size_t)(m0 + row) * K + k0 + (src_cb >> 1)),
          (las_t*)(As + rbase * 64), 16, 0, 0);
    }
#pragma unroll
    for (int i = 0; i < 2; ++i) {
      const int rbase = wid * 16 + i * 8;
      const int row = rbase + srow_off;
      const int src_cb = scb ^ ((row & 7) << 4);
      __builtin_amdgcn_global_load_lds(
          (gas_t*)(Bw + (size_t)(n0 + row) * K + k0 + (src_cb >> 1)),
          (las_t*)(Bs + rbase * 64), 16, 0, 0);
    }
    __syncthreads();
#pragma unroll
    for (int s = 0; s < 2; ++s) {
      const int kg = (s << 6) | ((lane >> 4) << 4);
      bf16x8 af[4], bfr[2];
#pragma unroll
      for (int m = 0; m < 4; ++m) {
        const int row = wm + m * 16 + (lane & 15);
        const int cb  = kg ^ ((row & 7) << 4);
        af[m] = *(const bf16x8*)((const char*)As + row * 128 + cb);
      }
#pragma unroll
      for (int n = 0; n < 2; ++n) {
        const int row = wn + n * 16 + (lane & 15);
        const int cb  = kg ^ ((row & 7) << 4);
        bfr[n] = *(const bf16x8*)((const char*)Bs + row * 128 + cb);
      }
#pragma unroll
      for (int m = 0; m < 4; ++m)
#pragma unroll
        for (int n = 0; n < 2; ++n)
          acc[m][n] = MFMA(af[m], bfr[n], acc[m][n]);
    }
    __syncthreads();
  }
  const int col = lane & 15;
  const int rb  = (lane >> 4) * 4;
#pragma unroll
  for (int m = 0; m < 4; ++m)
#pragma unroll
    for (int n = 0; n < 2; ++n) {
      float* cp = C + (size_t)(m0 + wm + m * 16 + rb) * ldc + n0 + wn + n * 16 + col;
      cp[0 * (size_t)ldc] = acc[m][n][0];
      cp[1 * (size_t)ldc] = acc[m][n][1];
      cp[2 * (size_t)ldc] = acc[m][n][2];
      cp[3 * (size_t)ldc] = acc[m][n][3];
    }
}

// ---------------------------------------------------------------------------
// Per-chunk summary via MFMA hi/lo:
//   dST[v][kk] = sum_t V[t][v] * k[t][kk]*exp(B63[kk]-B_t[kk])
// Grid (32,4,4), 256 thr. B from precomputed Bcum.
// ---------------------------------------------------------------------------
__global__ __launch_bounds__(256) void chunk_summary(
    const float* __restrict__ proj, const float* __restrict__ Bcum,
    float* __restrict__ dST) {
  __shared__ float bls[64];
  __shared__ __hip_bfloat16 kTh[64][72], kTl[64][72];   // ktw^T [kk][t]
  __shared__ __hip_bfloat16 vTh[128][72], vTl[128][72]; // V^T  [v][t]
  const int c = blockIdx.x, h = blockIdx.y, b = blockIdx.z;
  const int bh = b * NH + h;
  const int tid = threadIdx.x;
  const size_t rowbase = (size_t)b * TSEQ + (size_t)c * CHK;
  if (tid < 64) bls[tid] = Bcum[(rowbase + 63) * KD + h * HK + tid];
  __syncthreads();
  {
    const int t = tid >> 2;
    const int kk0 = (tid & 3) * 16;
    const float* kp = &proj[(rowbase + t) * LDP + KD + h * HK + kk0];
    const float* Bp = &Bcum[(rowbase + t) * KD + h * HK + kk0];
    float kv[16], Bv[16];
#pragma unroll
    for (int e4 = 0; e4 < 4; ++e4) {
      *(float4*)&kv[e4 * 4] = *(const float4*)(kp + e4 * 4);
      *(float4*)&Bv[e4 * 4] = *(const float4*)(Bp + e4 * 4);
    }
#pragma unroll
    for (int e = 0; e < 16; ++e) {
      const int kk = kk0 + e;
      const float val = kv[e] * expf(bls[kk] - Bv[e]);
      f2hl(val, kTh[kk][t], kTl[kk][t]);
    }
  }
#pragma unroll
  for (int base = 0; base < 8192; base += 1024) {
    const int idx = base + tid * 4;
    const int t = idx >> 7, v = idx & 127;
    const float4 vv = *(const float4*)&proj[(rowbase + t) * LDP + 2 * KD + h * HV + v];
    f2hl(vv.x, vTh[v + 0][t], vTl[v + 0][t]);
    f2hl(vv.y, vTh[v + 1][t], vTl[v + 1][t]);
    f2hl(vv.z, vTh[v + 2][t], vTl[v + 2][t]);
    f2hl(vv.w, vTh[v + 3][t], vTl[v + 3][t]);
  }
  __syncthreads();
  const int wid = tid >> 6, lane = tid & 63;
  const int lr = lane & 15, lkb = (lane >> 4) * 8;
  f32x4 acc[2][4];
#pragma unroll
  for (int m = 0; m < 2; ++m)
#pragma unroll
    for (int n = 0; n < 4; ++n) acc[m][n] = (f32x4){0.f, 0.f, 0.f, 0.f};
#pragma unroll
  for (int ks = 0; ks < 2; ++ks) {
    const int kt = ks * 32 + lkb;
    bf16x8 ah[2], al[2], bh_[4], bl_[4];
#pragma unroll
    for (int m = 0; m < 2; ++m) {
      ah[m] = *(const bf16x8*)&vTh[wid * 32 + m * 16 + lr][kt];
      al[m] = *(const bf16x8*)&vTl[wid * 32 + m * 16 + lr][kt];
    }
#pragma unroll
    for (int n = 0; n < 4; ++n) {
      bh_[n] = *(const bf16x8*)&kTh[n * 16 + lr][kt];
      bl_[n] = *(const bf16x8*)&kTl[n * 16 + lr][kt];
    }
#pragma unroll
    for (int m = 0; m < 2; ++m)
#pragma unroll
      for (int n = 0; n < 4; ++n) {
        acc[m][n] = MFMA(ah[m], bh_[n], acc[m][n]);
        acc[m][n] = MFMA(ah[m], bl_[n], acc[m][n]);
        acc[m][n] = MFMA(al[m], bh_[n], acc[m][n]);
      }
  }
  const int rb = (lane >> 4) * 4;
  float* outb = dST + ((size_t)bh * NC + c) * 8192;
#pragma unroll
  for (int m = 0; m < 2; ++m)
#pragma unroll
    for (int n = 0; n < 4; ++n)
#pragma unroll
      for (int i = 0; i < 4; ++i)
        outb[(wid * 32 + m * 16 + rb + i) * 64 + n * 16 + lr] = acc[m][n][i];
}

// ---------------------------------------------------------------------------
// Inter-chunk state propagation (transposed layout), emits bf16 hi/lo S.
// ---------------------------------------------------------------------------
__global__ __launch_bounds__(256) void state_prop(
    const float* __restrict__ dST, const float* __restrict__ dvec,
    __hip_bfloat16* __restrict__ ShT, __hip_bfloat16* __restrict__ SlT) {
  const int g  = blockIdx.x * 256 + threadIdx.x;  // 0..131071
  const int bh = g >> 13;
  const int el = g & 8191;        // el = v*64 + kk
  const int kk = el & 63;
  float S = 0.f;
  size_t base = (size_t)bh * NC * 8192 + el;
  const float* dv = dvec + (size_t)bh * NC * HK + kk;
  float dnext = dST[base];
  float vnext = dv[0];
  for (int c = 0; c < NC; ++c) {
    const float dcur = dnext, vcur = vnext;
    if (c + 1 < NC) {
      dnext = dST[base + 8192];
      vnext = dv[(size_t)(c + 1) * HK];
    }
    __hip_bfloat16 h, l;
    f2hl(S, h, l);
    ShT[base] = h; SlT[base] = l;
    S = S * vcur + dcur;
    base += 8192;
  }
}

// ---------------------------------------------------------------------------
// Per-chunk output via MFMA hi/lo: o = P@V + (q*scale*e^B)@S_prev, fused
// per-head RMSNorm * gnorm_w * silu(g), emits bf16 og. Grid (32,4,4), 256 thr.
// ---------------------------------------------------------------------------
__global__ __launch_bounds__(256) void chunk_output(
    const float* __restrict__ proj, const float* __restrict__ Bcum,
    const __hip_bfloat16* __restrict__ ShT, const __hip_bfloat16* __restrict__ SlT,
    const float* __restrict__ gnw, __hip_bfloat16* __restrict__ og) {
  __shared__ __align__(16) char smem_co[73984];
  __hip_bfloat16 (*qh)[72]  = (__hip_bfloat16(*)[72])(smem_co);        // [64][72]
  __hip_bfloat16 (*ql)[72]  = (__hip_bfloat16(*)[72])(smem_co + 9216);
  __hip_bfloat16 (*Ph)[72]  = (__hip_bfloat16(*)[72])(smem_co + 18432);
  __hip_bfloat16 (*Pl)[72]  = (__hip_bfloat16(*)[72])(smem_co + 27648);
  __hip_bfloat16 (*kh)[72]  = (__hip_bfloat16(*)[72])(smem_co + 36864); // transient
  __hip_bfloat16 (*kl)[72]  = (__hip_bfloat16(*)[72])(smem_co + 46080);
  __hip_bfloat16 (*vTh)[72] = (__hip_bfloat16(*)[72])(smem_co + 36864); // over kh/kl
  __hip_bfloat16 (*vTl)[72] = (__hip_bfloat16(*)[72])(smem_co + 55296);
  const int c = blockIdx.x, h = blockIdx.y, b = blockIdx.z;
  const int bh = b * NH + h;
  const int tid = threadIdx.x;
  const size_t rowbase = (size_t)b * TSEQ + (size_t)c * CHK;
  // phase 1: qt = q*scale*e^B (hi/lo), kt = k*e^{-B} (hi/lo), B from Bcum
  {
    const int t = tid >> 2;
    const int kk0 = (tid & 3) * 16;
    const float* qp = &proj[(rowbase + t) * LDP + h * HK + kk0];
    const float* Bp = &Bcum[(rowbase + t) * KD + h * HK + kk0];
    float qv[16], kv[16], Bv[16];
#pragma unroll
    for (int e4 = 0; e4 < 4; ++e4) {
      *(float4*)&qv[e4 * 4] = *(const float4*)(qp + e4 * 4);
      *(float4*)&kv[e4 * 4] = *(const float4*)(qp + KD + e4 * 4);
      *(float4*)&Bv[e4 * 4] = *(const float4*)(Bp + e4 * 4);
    }
#pragma unroll
    for (int e = 0; e < 16; ++e) {
      const int kk = kk0 + e;
      f2hl(qv[e] * 0.125f * expf(Bv[e]), qh[t][kk], ql[t][kk]);
      f2hl(kv[e] * expf(-Bv[e]),         kh[t][kk], kl[t][kk]);
    }
  }
  __syncthreads();
  const int wid = tid >> 6, lane = tid & 63;
  const int lr = lane & 15, lkb = (lane >> 4) * 8;
  const int rb = (lane >> 4) * 4;
  // phase 2: P = qt @ kt^T (masked), -> Ph/Pl
  {
    f32x4 pacc[4];
#pragma unroll
    for (int n = 0; n < 4; ++n) pacc[n] = (f32x4){0.f, 0.f, 0.f, 0.f};
#pragma unroll
    for (int ks = 0; ks < 2; ++ks) {
      const int kt = ks * 32 + lkb;
      const bf16x8 aqh = *(const bf16x8*)&qh[wid * 16 + lr][kt];
      const bf16x8 aql = *(const bf16x8*)&ql[wid * 16 + lr][kt];
#pragma unroll
      for (int n = 0; n < 4; ++n) {
        const bf16x8 bkh = *(const bf16x8*)&kh[n * 16 + lr][kt];
        const bf16x8 bkl = *(const bf16x8*)&kl[n * 16 + lr][kt];
        pacc[n] = MFMA(aqh, bkh, pacc[n]);
        pacc[n] = MFMA(aqh, bkl, pacc[n]);
        pacc[n] = MFMA(aql, bkh, pacc[n]);
      }
    }
#pragma unroll
    for (int n = 0; n < 4; ++n)
#pragma unroll
      for (int i = 0; i < 4; ++i) {
        const int r = wid * 16 + rb + i;
        const int j = n * 16 + lr;
        const float v = (j <= r) ? pacc[n][i] : 0.f;
        f2hl(v, Ph[r][j], Pl[r][j]);
      }
  }
  __syncthreads();
  // phase 3: V^T hi/lo (overwrites kh/kl)
#pragma unroll
  for (int base = 0; base < 8192; base += 1024) {
    const int idx = base + tid * 4;
    const int t = idx >> 7, v = idx & 127;
    const float4 vv = *(const float4*)&proj[(rowbase + t) * LDP + 2 * KD + h * HV + v];
    f2hl(vv.x, vTh[v + 0][t], vTl[v + 0][t]);
    f2hl(vv.y, vTh[v + 1][t], vTl[v + 1][t]);
    f2hl(vv.z, vTh[v + 2][t], vTl[v + 2][t]);
    f2hl(vv.w, vTh[v + 3][t], vTl[v + 3][t]);
  }
  __syncthreads();
  // phase 4: o = qt@S^T + P@V
  f32x4 oacc[8];
#pragma unroll
  for (int n = 0; n < 8; ++n) oacc[n] = (f32x4){0.f, 0.f, 0.f, 0.f};
  const __hip_bfloat16* Sh = ShT + ((size_t)bh * NC + c) * 8192;
  const __hip_bfloat16* Sl = SlT + ((size_t)bh * NC + c) * 8192;
#pragma unroll
  for (int ks = 0; ks < 2; ++ks) {
    const int kt = ks * 32 + lkb;
    const bf16x8 aqh = *(const bf16x8*)&qh[wid * 16 + lr][kt];
    const bf16x8 aql = *(const bf16x8*)&ql[wid * 16 + lr][kt];
#pragma unroll
    for (int n = 0; n < 8; ++n) {
      const int v = n * 16 + lr;
      const bf16x8 sh = *(const bf16x8*)(Sh + v * 64 + kt);
      const bf16x8 sl = *(const bf16x8*)(Sl + v * 64 + kt);
      oacc[n] = MFMA(aqh, sh, oacc[n]);
      oacc[n] = MFMA(aqh, sl, oacc[n]);
      oacc[n] = MFMA(aql, sh, oacc[n]);
    }
  }
#pragma unroll
  for (int ks = 0; ks < 2; ++ks) {
    const int kt = ks * 32 + lkb;
    const bf16x8 aph = *(const bf16x8*)&Ph[wid * 16 + lr][kt];
    const bf16x8 apl = *(const bf16x8*)&Pl[wid * 16 + lr][kt];
#pragma unroll
    for (int n = 0; n < 8; ++n) {
      const bf16x8 bvh = *(const bf16x8*)&vTh[n * 16 + lr][kt];
      const bf16x8 bvl = *(const bf16x8*)&vTl[n * 16 + lr][kt];
      oacc[n] = MFMA(aph, bvh, oacc[n]);
      oacc[n] = MFMA(aph, bvl, oacc[n]);
      oacc[n] = MFMA(apl, bvh, oacc[n]);
    }
  }
  // epilogue: per-row RMSNorm over 128 v (reduce across 16-lane group)
  float ss[4] = {0.f, 0.f, 0.f, 0.f};
#pragma unroll
  for (int n = 0; n < 8; ++n)
#pragma unroll
    for (int i = 0; i < 4; ++i) ss[i] += oacc[n][i] * oacc[n][i];
#pragma unroll
  for (int i = 0; i < 4; ++i) {
    ss[i] += __shfl_xor(ss[i], 1);
    ss[i] += __shfl_xor(ss[i], 2);
    ss[i] += __shfl_xor(ss[i], 4);
    ss[i] += __shfl_xor(ss[i], 8);
  }
  float rn[4];
#pragma unroll
  for (int i = 0; i < 4; ++i) rn[i] = rsqrtf(ss[i] * (1.0f / 128.0f) + 1e-5f);
#pragma unroll
  for (int n = 0; n < 8; ++n) {
    const int v = n * 16 + lr;
    const float w = gnw[v];  // gnorm_w is [HV], broadcast across heads
#pragma unroll
    for (int i = 0; i < 4; ++i) {
      const size_t grow = rowbase + wid * 16 + rb + i;
      const float g = proj[grow * LDP + 2 * VDIM + h * HV + v];
      const float sil = g / (1.f + expf(-g));
      og[grow * VDIM + h * HV + v] = __float2bfloat16(oacc[n][i] * rn[i] * w * sil);
    }
  }
}

// ---------------------------------------------------------------------------
extern "C" void kernel_launch(void* const* d_in, const int* in_sizes, int n_in,
                              void* d_out, int out_size, void* d_ws, size_t ws_size,
                              hipStream_t stream) {
  const float* X    = (const float*)d_in[0];
  const float* Wq   = (const float*)d_in[1];
  const float* Wk   = (const float*)d_in[2];
  const float* Wv   = (const float*)d_in[3];
  const float* Wgk1 = (const float*)d_in[4];
  const float* Wgk2 = (const float*)d_in[5];
  const float* bgk2 = (const float*)d_in[6];
  const float* gnw  = (const float*)d_in[7];
  const float* Wg   = (const float*)d_in[8];
  const float* Wo   = (const float*)d_in[9];
  float* out = (float*)d_out;

  char* wsb = (char*)d_ws;
  float* proj = (float*)(wsb);                              // 50331648 B
  float* Bcum = (float*)(wsb + 50331648);                   //  8388608 B
  float* g1   = (float*)(wsb + 58720256);                   //   524288 B
  float* dST  = (float*)(wsb + 59244544);                   // 16777216 B
  float* dvec = (float*)(wsb + 76021760);                   //   131072 B
  __hip_bfloat16* ShT  = (__hip_bfloat16*)(wsb + 76152832); //  8388608 B
  __hip_bfloat16* SlT  = (__hip_bfloat16*)(wsb + 84541440); //  8388608 B
  __hip_bfloat16* Xb   = (__hip_bfloat16*)(wsb + 92930048); //  8388608 B
  __hip_bfloat16* Wcat = (__hip_bfloat16*)(wsb + 101318656);//  2097152 B (incl Wo)
  __hip_bfloat16* Wob  = Wcat + 786432;
  __hip_bfloat16* ogb  = (__hip_bfloat16*)dST;  // alias: dST dead before chunk_output

  const dim3 blk(256);
  prep<<<dim3(1536), blk, 0, stream>>>(X, Wq, Wk, Wv, Wg, Wo, Wgk1, Xb, Wcat, g1);
  gemm_gate<<<dim3(896), blk, 0, stream>>>(Xb, Wcat, proj, HIDD, LDP, 12, 768,
                                           g1, Wgk2, bgk2, Bcum, dvec);
  chunk_summary<<<dim3(NC, NH, BATCH), blk, 0, stream>>>(proj, Bcum, dST);
  state_prop<<<dim3(512), blk, 0, stream>>>(dST, dvec, ShT, SlT);
  chunk_output<<<dim3(NC, NH, BATCH), blk, 0, stream>>>(proj, Bcum, ShT, SlT, gnw, ogb);
  gemm_n64<<<dim3(512), blk, 0, stream>>>(ogb, Wob, out, VDIM, VDIM);
}